// Round 1
// baseline (295.565 us; speedup 1.0000x reference)
//
#include <hip/hip_runtime.h>

#define B_SZ   256
#define S_SZ   4096
#define H_SZ   64
#define NCHUNK 16
#define CHUNK  (S_SZ / NCHUNK)   // 256

// delta = atan2(sin(p), cos(p)) == p - 2*pi*rint(p/(2*pi))  (principal wrap)
__device__ __forceinline__ float wrap_delta(float p) {
    const float INV2PI   = 0.15915494309189535f;
    const float TWOPI_HI = 6.2831854820251465f;     // float(2*pi)
    const float TWOPI_LO = -1.7484556000744887e-7f; // 2*pi - TWOPI_HI
    float n = rintf(p * INV2PI);
    float d = fmaf(n, -TWOPI_HI, p);
    d = fmaf(n, -TWOPI_LO, d);
    return d;
}

// Pass 1: per-(b,chunk,h) raw delta sums -> ws[(b*NCHUNK+chunk)*64 + h]
__global__ __launch_bounds__(256) void k_partials(
    const float* __restrict__ x, const float* __restrict__ W_e,
    const float* __restrict__ b_e, float* __restrict__ ws)
{
    int tid   = blockIdx.x * 256 + threadIdx.x;
    int wid   = tid >> 6;                // global wave id = (b, chunk)
    int lane  = threadIdx.x & 63;        // lane = h
    int b     = wid >> 4;                // wid / NCHUNK
    int chunk = wid & (NCHUNK - 1);

    float we = W_e[lane];
    float be = b_e[lane];

    const float* xp = x + b * S_SZ + chunk * CHUNK;
    float acc = 0.f;
    for (int r = 0; r < CHUNK / 64; ++r) {
        float xv = xp[r * 64 + lane];    // coalesced; one load per 64 s-steps
        #pragma unroll
        for (int j = 0; j < 64; ++j) {
            float xs = __shfl(xv, j, 64);          // broadcast x[b, s]
            float p  = fmaf(xs, we, be);
            acc += wrap_delta(p);
        }
    }
    ws[wid * 64 + lane] = acc;
}

// Pass 2: recompute deltas, add chunk-prefix base, stream Hseq; last chunk
// of each b also computes out[b].
__global__ __launch_bounds__(256) void k_scan(
    const float* __restrict__ x, const float* __restrict__ W_e,
    const float* __restrict__ b_e, const float* __restrict__ omega,
    const float* __restrict__ W_r, const float* __restrict__ b_r,
    const float* __restrict__ ws, float* __restrict__ out,
    float* __restrict__ hseq)
{
    int tid   = blockIdx.x * 256 + threadIdx.x;
    int wid   = tid >> 6;
    int lane  = threadIdx.x & 63;        // lane = h
    int b     = wid >> 4;
    int chunk = wid & (NCHUNK - 1);

    float we = W_e[lane];
    float be = b_e[lane];
    float om = omega[lane];

    // exclusive prefix of chunk sums for this (b, h)
    float base = 0.f;
    for (int c = 0; c < chunk; ++c)
        base += ws[(b * NCHUNK + c) * 64 + lane];   // coalesced
    float obase = om * base;

    const float* xp = x + b * S_SZ + chunk * CHUNK;
    float* hp = hseq + ((size_t)(b * S_SZ + chunk * CHUNK)) * H_SZ + lane;

    float acc = 0.f;
    float Hval = 0.f;
    for (int r = 0; r < CHUNK / 64; ++r) {
        float xv = xp[r * 64 + lane];
        #pragma unroll
        for (int j = 0; j < 64; ++j) {
            float xs = __shfl(xv, j, 64);
            float p  = fmaf(xs, we, be);
            acc += wrap_delta(p);
            Hval = fmaf(om, acc, obase);           // omega*(base+acc)
            __builtin_nontemporal_store(Hval, hp); // streaming, coalesced 256B/wave
            hp += H_SZ;
        }
    }

    if (chunk == NCHUNK - 1) {
        // Hval == ph[b, lane] (H at s = S-1)
        float ph = Hval;
        float v = cosf(ph) * W_r[lane]
                + sinf(ph) * W_r[H_SZ + lane]
                + ph       * W_r[2 * H_SZ + lane];
        #pragma unroll
        for (int off = 32; off > 0; off >>= 1)
            v += __shfl_down(v, off, 64);
        if (lane == 0) out[b] = v + b_r[0];
    }
}

extern "C" void kernel_launch(void* const* d_in, const int* in_sizes, int n_in,
                              void* d_out, int out_size, void* d_ws, size_t ws_size,
                              hipStream_t stream) {
    const float* x     = (const float*)d_in[0];
    const float* W_e   = (const float*)d_in[1];
    const float* b_e   = (const float*)d_in[2];
    const float* omega = (const float*)d_in[3];
    const float* W_r   = (const float*)d_in[4];
    const float* b_r   = (const float*)d_in[5];

    float* out  = (float*)d_out;          // (B,1) = 256 floats first
    float* hseq = out + B_SZ;             // then (B,S,H)
    float* ws   = (float*)d_ws;           // needs B*NCHUNK*H*4 = 1 MiB

    dim3 blk(256);
    dim3 grid(B_SZ * NCHUNK / 4);         // 4096 waves, 4 waves/block -> 1024 blocks

    k_partials<<<grid, blk, 0, stream>>>(x, W_e, b_e, ws);
    k_scan<<<grid, blk, 0, stream>>>(x, W_e, b_e, omega, W_r, b_r, ws, out, hseq);
}

// Round 2
// 294.824 us; speedup vs baseline: 1.0025x; 1.0025x over previous
//
#include <hip/hip_runtime.h>

#define B_SZ   256
#define S_SZ   4096
#define H_SZ   64
#define NCHUNK 32
#define CHUNK  (S_SZ / NCHUNK)   // 128

#define INV2PI   0.15915494309189535f
#define TWOPI_HI 6.2831854820251465f       // float(2*pi)
#define TWOPI_LO (-1.7484556000744887e-7f) // 2*pi - TWOPI_HI (into fp32)

// Force a wave-uniform pointer into SGPRs so x reads go down the scalar path
// (s_load) instead of per-lane broadcast loads / ds_bpermute.
__device__ __forceinline__ const float* uniform_ptr(const float* p) {
    uint64_t u = (uint64_t)(uintptr_t)p;
    uint32_t lo = __builtin_amdgcn_readfirstlane((uint32_t)u);
    uint32_t hi = __builtin_amdgcn_readfirstlane((uint32_t)(u >> 32));
    return (const float*)(uintptr_t)(((uint64_t)hi << 32) | lo);
}

// Pass 1: per-(b,chunk,h) raw delta sums -> ws[wid*64 + h]
// sum(delta) = we*sum(x) + CHUNK*be - 2pi*sum(n),  n = rint(p/2pi) (same
// rounding expression as pass 2 so wrap-boundary picks are identical).
__global__ __launch_bounds__(256, 4) void k_partials(
    const float* __restrict__ x, const float* __restrict__ W_e,
    const float* __restrict__ b_e, float* __restrict__ ws)
{
    int tid   = blockIdx.x * 256 + threadIdx.x;
    int wid   = tid >> 6;
    int lane  = threadIdx.x & 63;        // lane = h
    int b     = wid >> 5;                // wid / NCHUNK
    int chunk = wid & (NCHUNK - 1);

    float we = W_e[lane];
    float be = b_e[lane];

    const float* xpu = uniform_ptr(x + b * S_SZ + chunk * CHUNK);
    float accN = 0.f;   // sum of wrap integers (exact: small ints in fp32)
    float accX = 0.f;   // wave-uniform sum of x (scalar-pipe friendly)
    #pragma unroll 16
    for (int j = 0; j < CHUNK; ++j) {
        float xs = xpu[j];
        float p  = fmaf(xs, we, be);
        accN += rintf(p * INV2PI);
        accX += xs;
    }
    float sP = fmaf(we, accX, (float)CHUNK * be);
    float d  = fmaf(accN, -TWOPI_HI, sP);
    d        = fmaf(accN, -TWOPI_LO, d);
    ws[wid * 64 + lane] = d;
}

// Pass 2: recompute deltas, add chunk-prefix base, stream Hseq; last chunk
// of each b also computes out[b].
__global__ __launch_bounds__(256, 4) void k_scan(
    const float* __restrict__ x, const float* __restrict__ W_e,
    const float* __restrict__ b_e, const float* __restrict__ omega,
    const float* __restrict__ W_r, const float* __restrict__ b_r,
    const float* __restrict__ ws, float* __restrict__ out,
    float* __restrict__ hseq)
{
    int tid   = blockIdx.x * 256 + threadIdx.x;
    int wid   = tid >> 6;
    int lane  = threadIdx.x & 63;        // lane = h
    int b     = wid >> 5;
    int chunk = wid & (NCHUNK - 1);

    float we = W_e[lane];
    float be = b_e[lane];
    float om = omega[lane];

    // exclusive prefix of chunk sums for this (b, h) — coalesced 256B reads
    float base = 0.f;
    for (int c = 0; c < chunk; ++c)
        base += ws[(b * NCHUNK + c) * 64 + lane];
    float obase = om * base;

    const float* xpu = uniform_ptr(x + b * S_SZ + chunk * CHUNK);
    float* hp = hseq + (size_t)(b * S_SZ + chunk * CHUNK) * H_SZ + lane;

    float acc  = 0.f;
    float Hval = obase;
    #pragma unroll 16
    for (int j = 0; j < CHUNK; ++j) {
        float xs = xpu[j];                      // scalar-path broadcast
        float p  = fmaf(xs, we, be);
        float n  = rintf(p * INV2PI);           // same rounding as pass 1
        float d0 = fmaf(n, -TWOPI_HI, p);
        d0       = fmaf(n, -TWOPI_LO, d0);
        acc += d0;
        Hval = fmaf(om, acc, obase);            // omega*(base+acc)
        __builtin_nontemporal_store(Hval, hp + (size_t)j * H_SZ);
    }

    if (chunk == NCHUNK - 1) {
        float ph = Hval;                        // H at s = S-1 for h = lane
        float v = cosf(ph) * W_r[lane]
                + sinf(ph) * W_r[H_SZ + lane]
                + ph       * W_r[2 * H_SZ + lane];
        #pragma unroll
        for (int off = 32; off > 0; off >>= 1)
            v += __shfl_down(v, off, 64);
        if (lane == 0) out[b] = v + b_r[0];
    }
}

extern "C" void kernel_launch(void* const* d_in, const int* in_sizes, int n_in,
                              void* d_out, int out_size, void* d_ws, size_t ws_size,
                              hipStream_t stream) {
    const float* x     = (const float*)d_in[0];
    const float* W_e   = (const float*)d_in[1];
    const float* b_e   = (const float*)d_in[2];
    const float* omega = (const float*)d_in[3];
    const float* W_r   = (const float*)d_in[4];
    const float* b_r   = (const float*)d_in[5];

    float* out  = (float*)d_out;          // (B,1) = 256 floats first
    float* hseq = out + B_SZ;             // then (B,S,H)
    float* ws   = (float*)d_ws;           // needs B*NCHUNK*H*4 = 2 MiB

    dim3 blk(256);
    dim3 grid(B_SZ * NCHUNK / 4);         // 8192 waves / 4 per block = 2048 blocks

    k_partials<<<grid, blk, 0, stream>>>(x, W_e, b_e, ws);
    k_scan<<<grid, blk, 0, stream>>>(x, W_e, b_e, omega, W_r, b_r, ws, out, hseq);
}